// Round 1
// baseline (251.797 us; speedup 1.0000x reference)
//
#include <hip/hip_runtime.h>

// VectorQuantizer: inputs [32,256,2048] f32, weight [1024,256] f32
// out0 = quantized [32,256,2048] f32, out1 = argmin indices [65536] (as f32)
//
// Round 7: FUSE the X-prep into the MFMA kernel. Raw fp32 X is the same byte
// volume as Xh+Xl (4 B/elem), and a 32d x 128t raw tile is 16 KB = exactly the
// old per-step X staging. So:
//  - waves 2/3 stage RAW fp32 X rows via global_load_lds (per-lane global
//    addresses, 2 rows x 512 B per instruction),
//  - the fp16 hi/lo split happens in-register after the LDS read, with the
//    byte-identical expression prep used -> d2 bit-identical -> argmin same,
//  - xnorm is computed in-kernel during k-group 0 with the verified f64
//    ordering (half0 = d0..127 seq over steps 0..3, half1 = steps 4..7,
//    combine (float)(s0+s1)), one extra barrier at s==7 only,
//  - global source addresses are XOR-swizzled per row-octet (group ^= (d>>3)*2,
//    baked into the 8 staging pointers; LDS dest stays linear as required by
//    global_load_lds) so the strided b32 fragment reads are conflict-free
//    (2 lanes/bank).
// W-prep stays as a tiny 64-block kernel. Xh/Xl/xnorm workspace eliminated.
//
// Numerics (verified rounds 2-6, unchanged): dist = fp32( fp32(xnorm+wnorm)
// - fp32(2dot) ), dot = fp16x2-split 3-product MFMA, W pre-scaled by 1024
// (exact pow2), lo terms scaled 2^24; argmin strict '<' ascending k.

#define VQ_B   32
#define VQ_D   256
#define VQ_T   2048
#define VQ_K   1024

typedef _Float16 f16x8 __attribute__((ext_vector_type(8)));
typedef _Float16 f16x4 __attribute__((ext_vector_type(4)));
typedef float    f32x4 __attribute__((ext_vector_type(4)));

#define GLOAD_LDS16(gaddr, laddr) \
  __builtin_amdgcn_global_load_lds((const __attribute__((address_space(1))) void*)(gaddr), \
                                   (__attribute__((address_space(3))) void*)(laddr), 16, 0, 0)

// ---------------- kernel 1: W prep only (64 blocks), verified round-5 body.
__global__ __launch_bounds__(256) void vq_wprep_kernel(
    const float* __restrict__ w, float* __restrict__ wnorm,
    _Float16* __restrict__ Wh, _Float16* __restrict__ Wl)
{
    __shared__ double ws_[16][16];
    const int tid = threadIdx.x;
    const int kk  = tid >> 4;
    const int dg  = tid & 15;
    const int k   = blockIdx.x * 16 + kk;
    const float* src = w + (size_t)k * VQ_D + dg * 16;
    double s = 0.0;
    #pragma unroll
    for (int q = 0; q < 4; ++q) {
        float4 v = *(const float4*)(src + q * 4);
        s += (double)v.x * v.x + (double)v.y * v.y
           + (double)v.z * v.z + (double)v.w * v.w;
        const float e4[4] = {v.x, v.y, v.z, v.w};
        f16x4 hv, lv;
        #pragma unroll
        for (int j = 0; j < 4; ++j) {
            const float es = e4[j] * 1024.0f;          // exact pow2 scale
            const _Float16 h = (_Float16)es;
            hv[j] = h;
            lv[j] = (_Float16)((es - (float)h) * 16777216.0f);
        }
        *(f16x4*)(Wh + (size_t)k * VQ_D + dg * 16 + q * 4) = hv;
        *(f16x4*)(Wl + (size_t)k * VQ_D + dg * 16 + q * 4) = lv;
    }
    ws_[kk][dg] = s;
    __syncthreads();
    if (dg == 0) {
        double acc = 0.0;
        #pragma unroll
        for (int g = 0; g < 16; ++g) acc += ws_[kk][g];  // fixed order
        wnorm[k] = (float)acc;
    }
}

// ---------------- kernel 2: fused MFMA distance GEMM + argmin + gather
// 512 blocks, 4 waves (2x2), 128t x 128k tile, 64 linear (k0,d0) steps,
// double-buffered 2x32KB staging, one barrier per step.
// Staging buffer layout per 32KB half:
//   bytes     0..16383 : Wh (regions 0..7) + Wl (regions 8..15), as before
//   bytes 16384..32767 : RAW fp32 X tile, [32 d][128 t], row = 512 B,
//                        each row's sixteen 16B groups XOR-swizzled by
//                        (d>>3)*2 (baked into global src addresses).
__global__ __launch_bounds__(256, 2) void vq_mfma_kernel(
    const _Float16* __restrict__ Wh, const _Float16* __restrict__ Wl,
    const float* __restrict__ inp,
    const float* __restrict__ wnorm,
    const float* __restrict__ w,
    float* __restrict__ outq, float* __restrict__ outi)
{
    __shared__ alignas(16) char stg[2][32768];   // 2 x 32 regions x 1024 B
    __shared__ double xs[2][128];                // xnorm halves exchange
    const int tid  = threadIdx.x;
    const int lane = tid & 63;
    const int wv   = tid >> 6;                // wave 0..3
    const int m16  = lane & 15;
    const int quad = lane >> 4;
    const int wm   = wv & 1;                  // k half (waves 0/1), lo/hi sel
    const int wn   = wv >> 1;                 // t half
    const int b    = blockIdx.x >> 4;
    const int tt0  = (blockIdx.x & 15) * 128;
    const long bt  = (long)b * VQ_T + tt0;

    // 8 staging source pointers per wave: waves 0/1 = Wh/Wl (unchanged),
    // waves 2/3 = raw fp32 X rows (2 rows per GLOAD, lane>>5 = row parity,
    // lane&31 = 16B t-group, XOR-swizzled by the row-octet constant).
    const char* gp[8];
    #pragma unroll
    for (int i = 0; i < 8; ++i) {
        if (wv < 2) {
            const int hf = i >> 2, f = i & 3;
            const char* baseW = (const char*)((wv & 1) ? Wl : Wh);
            gp[i] = baseW + (size_t)(hf * 64 + f * 16 + m16) * 512 + quad * 16;
        } else {
            const int r  = (wv - 2) * 16 + i * 2 + (lane >> 5);  // in-step row 0..31
            const int sw = ((wv - 2) * 2 + (i >> 2)) * 2;        // = (r>>3)*2
            gp[i] = (const char*)inp
                  + ((size_t)b * VQ_D + r) * (size_t)(VQ_T * 4)
                  + (size_t)(tt0 * 4)
                  + (size_t)(((lane & 31) ^ sw) * 16);
        }
    }
    // advance after issuing step q: W +64B (next 32-d chunk), X +32 rows;
    // at chunk boundary W jumps k0+=128 and rewinds d, X rewinds d (net 0).
    auto advance = [&](int q) {
        if ((q & 7) == 7) {
            #pragma unroll
            for (int i = 0; i < 8; ++i)
                gp[i] += (wv < 2) ? (long)(65536 - 448) : (long)(-7) * 262144;
        } else {
            #pragma unroll
            for (int i = 0; i < 8; ++i)
                gp[i] += (wv < 2) ? 64L : 262144L;
        }
    };

    // per-fragment swizzled t-offset (float units) within a raw X row;
    // read swizzle (d>>3)*2 == quad*2 for d = quad*8+j, j<8.
    int tsw[4];
    #pragma unroll
    for (int f = 0; f < 4; ++f) {
        const int tl = wn * 64 + f * 16 + m16;
        tsw[f] = (((tl >> 2) ^ (quad * 2)) << 2) | (tl & 3);
    }

    // in-kernel xnorm: thread tid<128 owns t=tid, half0 (d 0..127, steps 0..3);
    // tid>=128 owns t=tid-128, half1 (d 128..255, steps 4..7). f64, sequential
    // d order — byte-identical to the retired prep kernel's accumulation.
    const int xt_t  = tid & 127;
    const int xhalf = tid >> 7;
    double xacc = 0.0;
    float  xnr[4];

    float bestv[4] = {3.0e38f, 3.0e38f, 3.0e38f, 3.0e38f};
    int   besti[4] = {0, 0, 0, 0};
    f32x4 acch[4][4], accl[4][4];

    // prologue: issue step 0 into buffer 0
    #pragma unroll
    for (int i = 0; i < 8; ++i)
        GLOAD_LDS16(gp[i], &stg[0][(wv * 8 + i) * 1024]);
    advance(0);

    for (int s = 0; s < 64; ++s) {
        const int cur = s & 1;
        if ((s & 7) == 0) {
            #pragma unroll
            for (int fm = 0; fm < 4; ++fm)
                #pragma unroll
                for (int fn = 0; fn < 4; ++fn) {
                    acch[fm][fn] = (f32x4){0.f, 0.f, 0.f, 0.f};
                    accl[fm][fn] = (f32x4){0.f, 0.f, 0.f, 0.f};
                }
        }
        __syncthreads();            // drains vmcnt -> stg[cur] resident
        if (s < 63) {               // prefetch step s+1 into the other buffer
            #pragma unroll
            for (int i = 0; i < 8; ++i)
                GLOAD_LDS16(gp[i], &stg[cur ^ 1][(wv * 8 + i) * 1024]);
            advance(s + 1);
        }

        const char*  base  = stg[cur];
        const float* xtile = (const float*)(base + 16384);  // [32][128] f32, swizzled

        f16x8 ah[4], al[4], bh[4], bl[4];
        #pragma unroll
        for (int f = 0; f < 4; ++f) {
            ah[f] = *(const f16x8*)(base + ((wm * 4 + f)) * 1024 + lane * 16);
            al[f] = *(const f16x8*)(base + ((8 + wm * 4 + f)) * 1024 + lane * 16);
        }
        // B fragments: raw fp32 -> hi/lo f16 split in-register (byte-identical
        // to old prep: h=(f16)x, l=(f16)((x-(float)h)*2^24)). Conflict-free:
        // per (f,j) read, 64 lanes land 2/bank thanks to the source swizzle.
        #pragma unroll
        for (int f = 0; f < 4; ++f) {
            f16x8 hv, lv;
            #pragma unroll
            for (int j = 0; j < 8; ++j) {
                const float x = xtile[(quad * 8 + j) * 128 + tsw[f]];
                const _Float16 h = (_Float16)x;
                hv[j] = h;
                lv[j] = (_Float16)((x - (float)h) * 16777216.0f);
            }
            bh[f] = hv; bl[f] = lv;
        }

        #pragma unroll
        for (int fm = 0; fm < 4; ++fm)
            #pragma unroll
            for (int fn = 0; fn < 4; ++fn) {
                acch[fm][fn] = __builtin_amdgcn_mfma_f32_16x16x32_f16(
                    ah[fm], bh[fn], acch[fm][fn], 0, 0, 0);
                accl[fm][fn] = __builtin_amdgcn_mfma_f32_16x16x32_f16(
                    ah[fm], bl[fn], accl[fm][fn], 0, 0, 0);
                accl[fm][fn] = __builtin_amdgcn_mfma_f32_16x16x32_f16(
                    al[fm], bh[fn], accl[fm][fn], 0, 0, 0);
            }

        // xnorm accumulation (k-group 0 only): this thread's half, ascending d.
        if (s < 8 && (s >> 2) == xhalf) {
            #pragma unroll
            for (int dd = 0; dd < 32; ++dd) {
                const float x = xtile[dd * 128 +
                    ((((xt_t >> 2) ^ ((dd >> 3) * 2)) << 2) | (xt_t & 3))];
                xacc += (double)x * (double)x;
            }
        }
        if (s == 7) {
            // exchange halves; combine exactly as prep did: (float)(s0 + s1)
            xs[xhalf][xt_t] = xacc;
            __syncthreads();        // one-time extra barrier (k-group 0 only)
            #pragma unroll
            for (int fn = 0; fn < 4; ++fn) {
                const int tl = wn * 64 + fn * 16 + m16;
                xnr[fn] = (float)(xs[0][tl] + xs[1][tl]);
            }
        }

        if ((s & 7) == 7) {
            const int k0 = (s >> 3) * 128;
            // scores, reference fp32 rounding chain; strict '<' over ascending
            // k => ties resolve to lowest index (matches np.argmin)
            #pragma unroll
            for (int fm = 0; fm < 4; ++fm) {
                #pragma unroll
                for (int r = 0; r < 4; ++r) {
                    const int kg = k0 + wm * 64 + fm * 16 + quad * 4 + r;
                    const float wnk = wnorm[kg];
                    #pragma unroll
                    for (int fn = 0; fn < 4; ++fn) {
                        const float t1 = xnr[fn] + wnk;
                        const float d2 = (acch[fm][fn][r]
                                          + accl[fm][fn][r] * 5.9604644775390625e-8f)
                                         * 0.001953125f;
                        const float sc = t1 - d2;
                        if (sc < bestv[fn]) { bestv[fn] = sc; besti[fn] = kg; }
                    }
                }
            }
        }
    }

    // cross-lane argmin: lanes {c, c+16, c+32, c+48} share a t-column
    float rv[4]; int ri[4];
    #pragma unroll
    for (int fn = 0; fn < 4; ++fn) {
        float bv = bestv[fn]; int bi = besti[fn];
        #pragma unroll
        for (int mask = 16; mask <= 32; mask <<= 1) {
            const float ov = __shfl_xor(bv, mask, 64);
            const int   oi = __shfl_xor(bi, mask, 64);
            if (ov < bv || (ov == bv && oi < bi)) { bv = ov; bi = oi; }
        }
        rv[fn] = bv; ri[fn] = bi;
    }

    // cross-wave (wm 0 vs 1) reduce via LDS overlay
    __syncthreads();
    float* sv = (float*)stg[0];              // [2][128]
    int*   si = (int*)(stg[0] + 1024);       // [2][128]
    if (quad == 0) {
        #pragma unroll
        for (int fn = 0; fn < 4; ++fn) {
            const int tl = wn * 64 + fn * 16 + m16;
            sv[wm * 128 + tl] = rv[fn];
            si[wm * 128 + tl] = ri[fn];
        }
    }
    __syncthreads();
    if (tid < 128) {
        const float v0 = sv[tid], v1 = sv[128 + tid];
        const int   i0 = si[tid], i1 = si[128 + tid];
        const int   bi = (v1 < v0 || (v1 == v0 && i1 < i0)) ? i1 : i0;
        si[tid] = bi;
        outi[bt + tid] = (float)bi;
    }
    __syncthreads();

    // quantized output: outq[b][d][t] = w[best[t]][d]  (verified epilogue)
    {
        const int t  = tid & 127;
        const int dh = tid >> 7;
        const int bi = si[t];
        const float* wrow = w + (size_t)bi * VQ_D + dh * 128;
        float* obase = outq + ((size_t)b * VQ_D + (size_t)dh * 128) * VQ_T + tt0 + t;
        #pragma unroll 4
        for (int dd = 0; dd < 128; dd += 4) {
            float4 v = *(const float4*)(wrow + dd);
            obase[(size_t)(dd + 0) * VQ_T] = v.x;
            obase[(size_t)(dd + 1) * VQ_T] = v.y;
            obase[(size_t)(dd + 2) * VQ_T] = v.z;
            obase[(size_t)(dd + 3) * VQ_T] = v.w;
        }
    }
}

extern "C" void kernel_launch(void* const* d_in, const int* in_sizes, int n_in,
                              void* d_out, int out_size, void* d_ws, size_t ws_size,
                              hipStream_t stream) {
    const float* inp = (const float*)d_in[0];
    const float* w   = (const float*)d_in[1];
    float* outq  = (float*)d_out;
    float* outi  = outq + (size_t)VQ_B * VQ_D * VQ_T;   // indices appended flat

    float*    wnorm = (float*)d_ws;                     // [1024]
    _Float16* Wh    = (_Float16*)(wnorm + VQ_K);        // [1024*256]
    _Float16* Wl    = Wh + (size_t)VQ_K * VQ_D;
    // total ws use: ~1.03 MB (Xh/Xl/xnorm eliminated)

    vq_wprep_kernel<<<dim3(VQ_K / 16), dim3(256), 0, stream>>>(w, wnorm, Wh, Wl);
    vq_mfma_kernel<<<dim3(VQ_B * (VQ_T / 128)), dim3(256), 0, stream>>>(
        Wh, Wl, inp, wnorm, w, outq, outi);
}

// Round 2
// 247.061 us; speedup vs baseline: 1.0192x; 1.0192x over previous
//
#include <hip/hip_runtime.h>

// VectorQuantizer: inputs [32,256,2048] f32, weight [1024,256] f32
// out0 = quantized [32,256,2048] f32, out1 = argmin indices [65536] (as f32)
//
// Round 8: LDS-PERSISTENT split-X. Round 7 showed inline per-fragment splitting
// is 16x redundant (2x wave-pair x 8 k-groups) and the b32 reads conflicted
// 2-way per phase (8.4M conflict cycles). Fix: shrink t-tile to 64 so the
// split X (64 t x 256 d x 4 B = 64 KB) fits LDS and is built ONCE per block:
//   - prologue: all 4 waves load raw X (once from HBM), split to f16 hi/lo
//     with the verified expression, ds_write into a b128-readable layout
//     (round-6's measured-0-conflict fragment pattern), and accumulate xnorm
//     in f64 (shfl tree-combined, (float) cast -> ulp-safe).
//   - main loop (8 kg x 8 chunks = 64 steps): only W is staged per step
//     (16 KB reg-staged into a single LDS region; loads for s+1 issued right
//     AFTER the barrier so the barrier's vmcnt drain has a full compute phase
//     of cover; 2 barriers/step for the single-buffer write/read hazard).
// LDS/block = Xh 32K + Xl 32K + Wbuf 16K = 80 KB -> 2 blocks/CU (160 KB exact).
// X re-fetch (8x from L2) and redundant split VALU are both eliminated.
//
// Numerics (verified rounds 2-7, unchanged): dist = fp32( fp32(xnorm+wnorm)
// - fp32(2dot) ), dot = fp16x2-split 3-product MFMA in chunk-ascending order
// (hi; ah*bl; al*bh), W pre-scaled by 1024 (exact pow2), lo terms scaled 2^24;
// argmin strict '<' ascending k + index-min tie-break.

#define VQ_B   32
#define VQ_D   256
#define VQ_T   2048
#define VQ_K   1024

typedef _Float16 f16x8 __attribute__((ext_vector_type(8)));
typedef _Float16 f16x4 __attribute__((ext_vector_type(4)));
typedef float    f32x4 __attribute__((ext_vector_type(4)));

// ---------------- kernel 1: W prep only (64 blocks), verified round-5 body.
__global__ __launch_bounds__(256) void vq_wprep_kernel(
    const float* __restrict__ w, float* __restrict__ wnorm,
    _Float16* __restrict__ Wh, _Float16* __restrict__ Wl)
{
    __shared__ double ws_[16][16];
    const int tid = threadIdx.x;
    const int kk  = tid >> 4;
    const int dg  = tid & 15;
    const int k   = blockIdx.x * 16 + kk;
    const float* src = w + (size_t)k * VQ_D + dg * 16;
    double s = 0.0;
    #pragma unroll
    for (int q = 0; q < 4; ++q) {
        float4 v = *(const float4*)(src + q * 4);
        s += (double)v.x * v.x + (double)v.y * v.y
           + (double)v.z * v.z + (double)v.w * v.w;
        const float e4[4] = {v.x, v.y, v.z, v.w};
        f16x4 hv, lv;
        #pragma unroll
        for (int j = 0; j < 4; ++j) {
            const float es = e4[j] * 1024.0f;          // exact pow2 scale
            const _Float16 h = (_Float16)es;
            hv[j] = h;
            lv[j] = (_Float16)((es - (float)h) * 16777216.0f);
        }
        *(f16x4*)(Wh + (size_t)k * VQ_D + dg * 16 + q * 4) = hv;
        *(f16x4*)(Wl + (size_t)k * VQ_D + dg * 16 + q * 4) = lv;
    }
    ws_[kk][dg] = s;
    __syncthreads();
    if (dg == 0) {
        double acc = 0.0;
        #pragma unroll
        for (int g = 0; g < 16; ++g) acc += ws_[kk][g];  // fixed order
        wnorm[k] = (float)acc;
    }
}

// ---------------- kernel 2: persistent-X MFMA distance GEMM + argmin + gather
// 1024 blocks (b = blk>>5, t-tile 64), 256 threads (4 waves: wm = k-half,
// wn = t-half-of-64). Wave tile = 64 k x 32 t (frags 4x2).
// LDS: [0,32K) Xh  [32K,64K) Xl  (layout: ((c*4+oct)*64 + t)*16B, oct=d-octet)
//      [64K,80K) Wbuf: 16 regions x 1024 B (regions 0-7 Wh, 8-15 Wl;
//                region = hf*4+f holds k = hf*64+f*16+m16 at (quad*16+m16)*16)
__global__ __launch_bounds__(256, 2) void vq_mfma_kernel(
    const _Float16* __restrict__ Wh, const _Float16* __restrict__ Wl,
    const float* __restrict__ inp,
    const float* __restrict__ wnorm,
    const float* __restrict__ w,
    float* __restrict__ outq, float* __restrict__ outi)
{
    __shared__ alignas(16) char lds[81920];
    char* Xh = lds;
    char* Xl = lds + 32768;
    char* Wb = lds + 65536;

    const int tid  = threadIdx.x;
    const int lane = tid & 63;
    const int wv   = tid >> 6;                // wave 0..3
    const int m16  = lane & 15;
    const int quad = lane >> 4;
    const int wm   = wv & 1;                  // k half (0..63 / 64..127)
    const int wn   = wv >> 1;                 // t half (0..31 / 32..63)
    const int b    = blockIdx.x >> 5;
    const int tt0  = (blockIdx.x & 31) * 64;
    const long bt  = (long)b * VQ_T + tt0;

    // ---- W reg-staging role: thread stages one k-row's 32-d chunk (64 B)
    // of Wh (tid<128) or Wl (tid>=128) per step.
    const int sel  = tid >> 7;
    const int r128 = tid & 127;
    const _Float16* wsrc = (sel ? Wl : Wh) + (size_t)r128 * VQ_D;
    char* wdst = Wb + (sel * 8 + (r128 >> 6) * 4 + ((r128 >> 4) & 3)) * 1024
               + (r128 & 15) * 16;

    // preload W for step 0 (kg=0, chunk 0)
    f16x8 wreg[4];
    #pragma unroll
    for (int q = 0; q < 4; ++q)
        wreg[q] = *(const f16x8*)(wsrc + q * 8);

    // ---- prologue: stage + split X once; accumulate xnorm (f64).
    // thread -> (t = m16 + wv*16, oct = quad); per chunk c it owns
    // d = c*32 + oct*8 + j, j=0..7 (ascending-d f64 accumulation).
    const int xt = m16 + wv * 16;
    double xacc = 0.0;
    {
        float xv[2][8];
        const float* xp0 = inp + ((size_t)b * VQ_D + quad * 8) * VQ_T + tt0 + xt;
        #pragma unroll
        for (int j = 0; j < 8; ++j)
            xv[0][j] = xp0[(size_t)j * VQ_T];
        #pragma unroll
        for (int c = 0; c < 8; ++c) {
            if (c < 7) {
                const float* xpn = inp
                    + ((size_t)b * VQ_D + (c + 1) * 32 + quad * 8) * VQ_T
                    + tt0 + xt;
                #pragma unroll
                for (int j = 0; j < 8; ++j)
                    xv[(c + 1) & 1][j] = xpn[(size_t)j * VQ_T];
            }
            f16x8 hv, lv;
            #pragma unroll
            for (int j = 0; j < 8; ++j) {
                const float x = xv[c & 1][j];
                xacc += (double)x * (double)x;             // ascending d
                const _Float16 h = (_Float16)x;
                hv[j] = h;
                lv[j] = (_Float16)((x - (float)h) * 16777216.0f);
            }
            const int off = ((c * 4 + quad) * 64 + xt) * 16;
            *(f16x8*)(Xh + off) = hv;
            *(f16x8*)(Xl + off) = lv;
        }
    }
    // combine the 4 oct-partials per t (lanes {m16+16q}); f64 tree is safe
    // at (float) granularity.
    xacc += __shfl_xor(xacc, 16, 64);
    xacc += __shfl_xor(xacc, 32, 64);
    {
        float* xns = (float*)Wb;                 // Wb free during prologue
        if (quad == 0) xns[xt] = (float)xacc;
    }
    __syncthreads();                             // X + xns visible
    float xnr[2];
    #pragma unroll
    for (int f = 0; f < 2; ++f)
        xnr[f] = ((const float*)Wb)[wn * 32 + f * 16 + m16];
    __syncthreads();                             // before Wb overwrite

    float bestv[2] = {3.0e38f, 3.0e38f};
    int   besti[2] = {0, 0};
    f32x4 acch[4][2], accl[4][2];

    // ---- main loop: 8 k-groups x 8 d-chunks. Only W staged per step.
    for (int s = 0; s < 64; ++s) {
        const int c = s & 7;
        // phase 1: publish W(s) from regs into the single Wbuf
        #pragma unroll
        for (int q = 0; q < 4; ++q)
            *(f16x8*)(wdst + q * 256) = wreg[q];
        __syncthreads();             // Wbuf(s) visible; prior reads done
        // phase 2: issue W(s+1) loads AFTER the barrier (vmcnt drain at the
        // NEXT barrier -> a full compute phase of latency cover)
        if (s < 63) {
            const int s1  = s + 1;
            const _Float16* src = wsrc
                + (size_t)((s1 >> 3) * 128) * VQ_D + (s1 & 7) * 32;
            #pragma unroll
            for (int q = 0; q < 4; ++q)
                wreg[q] = *(const f16x8*)(src + q * 8);
        }

        if (c == 0) {
            #pragma unroll
            for (int fm = 0; fm < 4; ++fm)
                #pragma unroll
                for (int fn = 0; fn < 2; ++fn) {
                    acch[fm][fn] = (f32x4){0.f, 0.f, 0.f, 0.f};
                    accl[fm][fn] = (f32x4){0.f, 0.f, 0.f, 0.f};
                }
        }

        f16x8 ah[4], al[4], bh[2], bl[2];
        #pragma unroll
        for (int fm = 0; fm < 4; ++fm) {
            ah[fm] = *(const f16x8*)(Wb + (wm * 4 + fm) * 1024 + lane * 16);
            al[fm] = *(const f16x8*)(Wb + (8 + wm * 4 + fm) * 1024 + lane * 16);
        }
        #pragma unroll
        for (int f = 0; f < 2; ++f) {
            const int off = ((c * 4 + quad) * 64 + wn * 32 + f * 16 + m16) * 16;
            bh[f] = *(const f16x8*)(Xh + off);
            bl[f] = *(const f16x8*)(Xl + off);
        }
        #pragma unroll
        for (int fm = 0; fm < 4; ++fm)
            #pragma unroll
            for (int fn = 0; fn < 2; ++fn) {
                acch[fm][fn] = __builtin_amdgcn_mfma_f32_16x16x32_f16(
                    ah[fm], bh[fn], acch[fm][fn], 0, 0, 0);
                accl[fm][fn] = __builtin_amdgcn_mfma_f32_16x16x32_f16(
                    ah[fm], bl[fn], accl[fm][fn], 0, 0, 0);
                accl[fm][fn] = __builtin_amdgcn_mfma_f32_16x16x32_f16(
                    al[fm], bh[fn], accl[fm][fn], 0, 0, 0);
            }

        if (c == 7) {
            const int k0 = (s >> 3) * 128;
            // scores, reference fp32 rounding chain; strict '<' over ascending
            // k => ties resolve to lowest index (matches np.argmin)
            #pragma unroll
            for (int fm = 0; fm < 4; ++fm) {
                #pragma unroll
                for (int r = 0; r < 4; ++r) {
                    const int kg = k0 + wm * 64 + fm * 16 + quad * 4 + r;
                    const float wnk = wnorm[kg];
                    #pragma unroll
                    for (int fn = 0; fn < 2; ++fn) {
                        const float t1 = xnr[fn] + wnk;
                        const float d2 = (acch[fm][fn][r]
                                          + accl[fm][fn][r] * 5.9604644775390625e-8f)
                                         * 0.001953125f;
                        const float sc = t1 - d2;
                        if (sc < bestv[fn]) { bestv[fn] = sc; besti[fn] = kg; }
                    }
                }
            }
        }
        __syncthreads();             // reads of Wbuf(s) done -> s+1 may write
    }

    // cross-lane argmin: lanes {c, c+16, c+32, c+48} share a t-column
    float rv[2]; int ri[2];
    #pragma unroll
    for (int fn = 0; fn < 2; ++fn) {
        float bv = bestv[fn]; int bi = besti[fn];
        #pragma unroll
        for (int mask = 16; mask <= 32; mask <<= 1) {
            const float ov = __shfl_xor(bv, mask, 64);
            const int   oi = __shfl_xor(bi, mask, 64);
            if (ov < bv || (ov == bv && oi < bi)) { bv = ov; bi = oi; }
        }
        rv[fn] = bv; ri[fn] = bi;
    }

    // cross-wave (wm 0 vs 1) reduce via LDS overlay (X/W regions now dead;
    // the loop's final __syncthreads() ordered all reads before these writes)
    float* sv = (float*)lds;                 // [2][64]
    int*   si = (int*)(lds + 1024);          // [2][64]
    if (quad == 0) {
        #pragma unroll
        for (int fn = 0; fn < 2; ++fn) {
            const int tl = wn * 32 + fn * 16 + m16;
            sv[wm * 64 + tl] = rv[fn];
            si[wm * 64 + tl] = ri[fn];
        }
    }
    __syncthreads();
    if (tid < 64) {
        const float v0 = sv[tid], v1 = sv[64 + tid];
        const int   i0 = si[tid], i1 = si[64 + tid];
        const int   bi = (v1 < v0 || (v1 == v0 && i1 < i0)) ? i1 : i0;
        si[tid] = bi;
        outi[bt + tid] = (float)bi;
    }
    __syncthreads();

    // quantized output: outq[b][d][t] = w[best[t]][d]  (verified epilogue,
    // re-tiled: thread (t = tid&63, dq = tid>>6) writes 64 d-rows)
    {
        const int t  = tid & 63;
        const int dq = tid >> 6;
        const int bi = si[t];
        const float* wrow = w + (size_t)bi * VQ_D + dq * 64;
        float* obase = outq + ((size_t)b * VQ_D + (size_t)dq * 64) * VQ_T + tt0 + t;
        #pragma unroll 4
        for (int dd = 0; dd < 64; dd += 4) {
            float4 v = *(const float4*)(wrow + dd);
            obase[(size_t)(dd + 0) * VQ_T] = v.x;
            obase[(size_t)(dd + 1) * VQ_T] = v.y;
            obase[(size_t)(dd + 2) * VQ_T] = v.z;
            obase[(size_t)(dd + 3) * VQ_T] = v.w;
        }
    }
}

extern "C" void kernel_launch(void* const* d_in, const int* in_sizes, int n_in,
                              void* d_out, int out_size, void* d_ws, size_t ws_size,
                              hipStream_t stream) {
    const float* inp = (const float*)d_in[0];
    const float* w   = (const float*)d_in[1];
    float* outq  = (float*)d_out;
    float* outi  = outq + (size_t)VQ_B * VQ_D * VQ_T;   // indices appended flat

    float*    wnorm = (float*)d_ws;                     // [1024]
    _Float16* Wh    = (_Float16*)(wnorm + VQ_K);        // [1024*256]
    _Float16* Wl    = Wh + (size_t)VQ_K * VQ_D;
    // total ws use: ~1.03 MB

    vq_wprep_kernel<<<dim3(VQ_K / 16), dim3(256), 0, stream>>>(w, wnorm, Wh, Wl);
    vq_mfma_kernel<<<dim3(VQ_B * (VQ_T / 64)), dim3(256), 0, stream>>>(
        Wh, Wl, inp, wnorm, w, outq, outi);
}